// Round 6
// baseline (234.561 us; speedup 1.0000x reference)
//
#include <hip/hip_runtime.h>

typedef unsigned short u16;
typedef __attribute__((ext_vector_type(8))) short short8;   // 8 bf16 = 4 VGPRs
typedef __attribute__((ext_vector_type(4))) float f32x4;

#define D 2048
#define EPS 1e-5f

__device__ __forceinline__ u16 f2bf(float f) {
  unsigned u = __float_as_uint(f);
  u += 0x7fffu + ((u >> 16) & 1u);   // round-to-nearest-even
  return (u16)(u >> 16);
}

__device__ __forceinline__ void async16(const void* g, void* l) {
  __builtin_amdgcn_global_load_lds(
      (const __attribute__((address_space(1))) void*)g,
      (__attribute__((address_space(3))) void*)l, 16, 0, 0);
}

// ============ kernel 1: fused row-LN (out=x prefill) + weight transpose/cvt ============
__global__ __launch_bounds__(256) void prep(const float* __restrict__ x,
                                            const float* __restrict__ Wq,
                                            const float* __restrict__ Wk,
                                            const float* __restrict__ Wv,
                                            const float* __restrict__ Wo,
                                            u16* __restrict__ xn,
                                            float* __restrict__ out,
                                            u16* __restrict__ WqT, u16* __restrict__ WkT,
                                            u16* __restrict__ WvT, u16* __restrict__ WoT,
                                            unsigned* __restrict__ cnt) {
  int bid = blockIdx.x;
  int t = threadIdx.x;
  if (bid == 0 && t < 32) cnt[t] = 0;   // reset split-K arrival counters each iteration
  if (bid < 2048) {
    const float* xr = x + (size_t)bid * D;
    float4 v[2];
    float s = 0.f, sq = 0.f;
#pragma unroll
    for (int i = 0; i < 2; i++) {
      v[i] = *(const float4*)(xr + i * 1024 + t * 4);
      s += v[i].x + v[i].y + v[i].z + v[i].w;
      sq += v[i].x * v[i].x + v[i].y * v[i].y + v[i].z * v[i].z + v[i].w * v[i].w;
    }
#pragma unroll
    for (int m = 32; m >= 1; m >>= 1) { s += __shfl_xor(s, m); sq += __shfl_xor(sq, m); }
    __shared__ float ps[4], pq[4];
    int w = t >> 6, lane = t & 63;
    if (lane == 0) { ps[w] = s; pq[w] = sq; }
    __syncthreads();
    s = ps[0] + ps[1] + ps[2] + ps[3];
    sq = pq[0] + pq[1] + pq[2] + pq[3];
    float mean = s * (1.f / D);
    float var = sq * (1.f / D) - mean * mean;
    float rs = rsqrtf(var + EPS);
    float* outr = out + (size_t)bid * D;
    u16* xnr = xn + (size_t)bid * D;
#pragma unroll
    for (int i = 0; i < 2; i++) {
      *(float4*)(outr + i * 1024 + t * 4) = v[i];      // residual base
      ushort4 o;
      o.x = f2bf((v[i].x - mean) * rs);
      o.y = f2bf((v[i].y - mean) * rs);
      o.z = f2bf((v[i].z - mean) * rs);
      o.w = f2bf((v[i].w - mean) * rs);
      *(ushort4*)(xnr + i * 1024 + t * 4) = o;
    }
  } else {
    int tb = bid - 2048;
    int wsel = tb >> 10;
    int tt = tb & 1023;
    const float* src; u16* dst;
    switch (wsel) {
      case 0: src = Wq; dst = WqT; break;
      case 1: src = Wk; dst = WkT; break;
      case 2: src = Wv; dst = WvT; break;
      default: src = Wo; dst = WoT; break;
    }
    int i0 = (tt >> 5) * 64, j0 = (tt & 31) * 64;
    __shared__ u16 tile[64 * 66];
#pragma unroll
    for (int r = 0; r < 4; r++) {
      int idx = r * 256 + t;
      int row = idx >> 4, c4 = idx & 15;
      float4 v = *(const float4*)(src + (size_t)(i0 + row) * D + j0 + c4 * 4);
      tile[row * 66 + c4 * 4 + 0] = f2bf(v.x);
      tile[row * 66 + c4 * 4 + 1] = f2bf(v.y);
      tile[row * 66 + c4 * 4 + 2] = f2bf(v.z);
      tile[row * 66 + c4 * 4 + 3] = f2bf(v.w);
    }
    __syncthreads();
#pragma unroll
    for (int r = 0; r < 4; r++) {
      int idx = r * 256 + t;
      int row = idx >> 4, c4 = idx & 15;
      ushort4 o;
      o.x = tile[(c4 * 4 + 0) * 66 + row];
      o.y = tile[(c4 * 4 + 1) * 66 + row];
      o.z = tile[(c4 * 4 + 2) * 66 + row];
      o.w = tile[(c4 * 4 + 3) * 66 + row];
      *(ushort4*)(dst + (size_t)(j0 + row) * D + i0 + c4 * 4) = o;   // dst[n][k]=src[k][n]
    }
  }
}

// ============ single-buffered 128x128-tile bf16 MFMA GEMM body (m97 structure) ============
__device__ __forceinline__ void gemm_tile(const u16* __restrict__ A,
                                          const u16* __restrict__ Bt,
                                          bool permB, int m0, int n0,
                                          int kbeg, int kend,
                                          u16* As, u16* Bs, f32x4 acc[4][4]) {
  int tid = threadIdx.x, wid = tid >> 6, lane = tid & 63;
  int q4 = lane >> 4, m16 = lane & 15;
  int wm = wid >> 1, wn = wid & 1;
  for (int kb = kbeg; kb < kend; kb += 64) {
#pragma unroll
    for (int p = 0; p < 4; p++) {
      int idx = p * 256 + tid;         // chunk id 0..1023
      int r = idx >> 3, sl = idx & 7;
      int gc = sl ^ (r & 7);           // XOR-swizzled column chunk
      async16(A + (size_t)(m0 + r) * D + kb + gc * 8, As + (size_t)(p * 256 + wid * 64) * 8);
      int rb = n0 + r;
      int gr = permB ? ((rb & 127) * 16 + (rb >> 7)) : rb;  // token perm for V
      async16(Bt + (size_t)gr * D + kb + gc * 8, Bs + (size_t)(p * 256 + wid * 64) * 8);
    }
    __syncthreads();
#pragma unroll
    for (int ks = 0; ks < 2; ks++) {
      short8 af[4], bf[4];
      int c = ks * 4 + q4;
#pragma unroll
      for (int i = 0; i < 4; i++) {
        int ra = wm * 64 + i * 16 + m16;
        af[i] = *(const short8*)(As + ra * 64 + (c ^ (ra & 7)) * 8);
        int rb = wn * 64 + i * 16 + m16;
        bf[i] = *(const short8*)(Bs + rb * 64 + (c ^ (rb & 7)) * 8);
      }
#pragma unroll
      for (int i = 0; i < 4; i++)
#pragma unroll
        for (int j = 0; j < 4; j++)
          acc[i][j] = __builtin_amdgcn_mfma_f32_16x16x32_bf16(af[i], bf[j], acc[i][j], 0, 0, 0);
    }
    __syncthreads();
  }
}

// ============ kernel 2: K/V/Q mega-GEMM, 768 blocks = exactly 3/CU, balanced ============
// bid [0,512):   K/V full tiles (XCD-chunked swizzle), 32 K-steps each
// bid [512,768): Q split-K tiles: 2 m-tiles x 16 n-tiles x splitK=8, 4 K-steps each,
//                fp32 partials into Qp. Per-CU load: 2 fulls + 1 Q = 2.125 units.
__global__ __launch_bounds__(256, 3) void gemm_mega(const u16* __restrict__ xn,
                                                    const u16* __restrict__ WkT,
                                                    const u16* __restrict__ WvT,
                                                    const u16* __restrict__ WqT,
                                                    u16* __restrict__ K3,
                                                    u16* __restrict__ V3,
                                                    float* __restrict__ Qp) {
  __shared__ u16 smem[2 * 128 * 64];   // 32 KB
  u16* As = smem;
  u16* Bs = smem + 8192;
  int bid0 = blockIdx.x;
  int tid = threadIdx.x, wid = tid >> 6, lane = tid & 63;
  int q4 = lane >> 4, m16 = lane & 15;
  int wm = wid >> 1, wn = wid & 1;

  if (bid0 >= 512) {
    // ---- Q split-K blocks (1/8 weight) ----
    int qb = bid0 - 512;
    int ks = qb & 7, t = qb >> 3;            // ks: K-slice; t in [0,32)
    int m0 = (t >> 4) * 128, n0 = (t & 15) * 128;
    f32x4 acc[4][4];
#pragma unroll
    for (int i = 0; i < 4; i++)
#pragma unroll
      for (int j = 0; j < 4; j++)
#pragma unroll
        for (int r = 0; r < 4; r++) acc[i][j][r] = 0.f;
    gemm_tile(xn, WqT, false, m0, n0, ks * 256, ks * 256 + 256, As, Bs, acc);
    float* C = Qp + (size_t)ks * 256 * D;
#pragma unroll
    for (int i = 0; i < 4; i++)
#pragma unroll
      for (int j = 0; j < 4; j++)
#pragma unroll
        for (int r = 0; r < 4; r++) {
          int row = m0 + wm * 64 + i * 16 + q4 * 4 + r;
          int col = n0 + wn * 64 + j * 16 + m16;
          C[(size_t)row * D + col] = acc[i][j][r];
        }
    return;
  }

  int bid = (bid0 & 7) * 64 + (bid0 >> 3);   // bijective XCD chunking: 512 % 8 == 0
  int sel = bid >> 8;                  // 0: K-GEMM, 1: V-GEMM
  int z = bid & 255;
  int m0 = (z >> 4) * 128, n0 = (z & 15) * 128;
  const u16* A = sel ? WvT : xn;
  const u16* Bt = sel ? xn : WkT;
  f32x4 acc[4][4];
#pragma unroll
  for (int i = 0; i < 4; i++)
#pragma unroll
    for (int j = 0; j < 4; j++)
#pragma unroll
      for (int r = 0; r < 4; r++) acc[i][j][r] = 0.f;
  gemm_tile(A, Bt, sel == 1, m0, n0, 0, D, As, Bs, acc);

  if (sel == 1) {
    int h = m0 >> 7, b = n0 >> 7;
#pragma unroll
    for (int i = 0; i < 4; i++)
#pragma unroll
      for (int j = 0; j < 4; j++)
#pragma unroll
        for (int r = 0; r < 4; r++) {
          int dhl = wm * 64 + i * 16 + q4 * 4 + r;     // C/D: row=(lane>>4)*4+reg
          int key = wn * 64 + j * 16 + m16;            //      col=lane&15
          V3[((size_t)(h * 16 + b) * 128 + dhl) * 128 + key] = f2bf(acc[i][j][r]);
        }
  } else {
    // fused head-LN: rows = tokens, 128 cols = this head's dims (tile-aligned)
    float* redS = (float*)smem;        // [128][2]
    float* redQ = redS + 256;          // [128][2]
    __syncthreads();                   // smem free for reduction scratch
#pragma unroll
    for (int i = 0; i < 4; i++) {      // i-by-i to limit register liveness
      float ps[4], pq[4];
#pragma unroll
      for (int r = 0; r < 4; r++) {
        float s = 0.f, q = 0.f;
#pragma unroll
        for (int j = 0; j < 4; j++) { float a = acc[i][j][r]; s += a; q += a * a; }
#pragma unroll
        for (int msk = 1; msk < 16; msk <<= 1) {
          s += __shfl_xor(s, msk);
          q += __shfl_xor(q, msk);
        }
        ps[r] = s; pq[r] = q;
      }
      if (m16 == 0) {
#pragma unroll
        for (int r = 0; r < 4; r++) {
          int row = wm * 64 + i * 16 + q4 * 4 + r;
          redS[row * 2 + wn] = ps[r];
          redQ[row * 2 + wn] = pq[r];
        }
      }
    }
    __syncthreads();
    int h = n0 >> 7;
#pragma unroll
    for (int i = 0; i < 4; i++)
#pragma unroll
      for (int r = 0; r < 4; r++) {
        int row = wm * 64 + i * 16 + q4 * 4 + r;
        float S = redS[row * 2] + redS[row * 2 + 1];
        float Qs = redQ[row * 2] + redQ[row * 2 + 1];
        float mean = S * (1.f / 128.f);
        float var = Qs * (1.f / 128.f) - mean * mean;
        float rstd = rsqrtf(var + EPS);
        int tok = m0 + row;
#pragma unroll
        for (int j = 0; j < 4; j++) {
          int dhl = wn * 64 + j * 16 + m16;
          u16 val = f2bf((acc[i][j][r] - mean) * rstd);
          K3[(((size_t)(h * 16 + (tok & 15))) * 128 + (tok >> 4)) * 128 + dhl] = val;
        }
      }
  }
}

// ============ kernel 3: attention, 256 blocks=(b,h), 512 threads (8 waves) ============
__global__ __launch_bounds__(512) void attn(const float* __restrict__ Qp,
                                            const u16* __restrict__ K3,
                                            const u16* __restrict__ V3,
                                            u16* __restrict__ Ob) {
  int bh = blockIdx.x;
  int h = bh & 15, b = bh >> 4;
  int tid = threadIdx.x, w = tid >> 6, lane = tid & 63;
  int q4 = lane >> 4, m16 = lane & 15;
  __shared__ u16 Qs[16][136];
  __shared__ u16 P[16][136];
  __shared__ float redmx[8][16];
  __shared__ float redsm[8][16];
  __shared__ float invd[16];
  const float scale = 0.08838834764831845f;   // 1/sqrt(128)
  const u16* Ktile = K3 + (size_t)(h * 16 + b) * 128 * 128;
  const u16* Vtile = V3 + (size_t)(h * 16 + b) * 128 * 128;

  // ---- Qp reduce + head-LN: thread (row=tid>>5, 4 cols at (tid&31)*4)
  {
    int row = tid >> 5;
    int c4 = (tid & 31) * 4;
    const float* qpb = Qp + (size_t)(b * 16 + row) * D + h * 128 + c4;
    float q4v[4] = {0.f, 0.f, 0.f, 0.f};
#pragma unroll
    for (int ks = 0; ks < 8; ks++) {
      float4 a = *(const float4*)(qpb + (size_t)ks * 256 * D);
      q4v[0] += a.x; q4v[1] += a.y; q4v[2] += a.z; q4v[3] += a.w;
    }
    float s = 0.f, sq = 0.f;
#pragma unroll
    for (int ii = 0; ii < 4; ii++) { s += q4v[ii]; sq += q4v[ii] * q4v[ii]; }
#pragma unroll
    for (int msk = 1; msk < 32; msk <<= 1) { s += __shfl_xor(s, msk); sq += __shfl_xor(sq, msk); }
    float mean = s * (1.f / 128.f);
    float var = sq * (1.f / 128.f) - mean * mean;
    float rstd = rsqrtf(var + EPS);
    ushort4 o4;
    o4.x = f2bf((q4v[0] - mean) * rstd);
    o4.y = f2bf((q4v[1] - mean) * rstd);
    o4.z = f2bf((q4v[2] - mean) * rstd);
    o4.w = f2bf((q4v[3] - mean) * rstd);
    *(ushort4*)(&Qs[row][c4]) = o4;
  }
  __syncthreads();

  // ---- QK^T: wave w handles keys [16w, 16w+16)
  short8 af[4];
#pragma unroll
  for (int dc = 0; dc < 4; dc++)
    af[dc] = *(const short8*)(&Qs[m16][dc * 32 + q4 * 8]);
  f32x4 s1;
#pragma unroll
  for (int r = 0; r < 4; r++) s1[r] = 0.f;
  {
    int key = w * 16 + m16;
#pragma unroll
    for (int dc = 0; dc < 4; dc++) {
      short8 bf = *(const short8*)(Ktile + (size_t)key * 128 + dc * 32 + q4 * 8);
      s1 = __builtin_amdgcn_mfma_f32_16x16x32_bf16(af[dc], bf, s1, 0, 0, 0);
    }
  }
  float mx[4];
#pragma unroll
  for (int r = 0; r < 4; r++) {
    mx[r] = s1[r];
#pragma unroll
    for (int msk = 1; msk < 16; msk <<= 1) mx[r] = fmaxf(mx[r], __shfl_xor(mx[r], msk));
    if (m16 == 0) redmx[w][q4 * 4 + r] = mx[r];
  }
  __syncthreads();
#pragma unroll
  for (int r = 0; r < 4; r++) {
    int row = q4 * 4 + r;
    float M = fmaxf(fmaxf(fmaxf(redmx[0][row], redmx[1][row]), fmaxf(redmx[2][row], redmx[3][row])),
                    fmaxf(fmaxf(redmx[4][row], redmx[5][row]), fmaxf(redmx[6][row], redmx[7][row])));
    float e = __expf((s1[r] - M) * scale);
    s1[r] = e;
    float acc = e;
#pragma unroll
    for (int msk = 1; msk < 16; msk <<= 1) acc += __shfl_xor(acc, msk);
    if (m16 == 0) redsm[w][row] = acc;
  }
#pragma unroll
  for (int r = 0; r < 4; r++)
    P[q4 * 4 + r][w * 16 + m16] = f2bf(s1[r]);
  __syncthreads();
  if (tid < 16)
    invd[tid] = 1.0f / (redsm[0][tid] + redsm[1][tid] + redsm[2][tid] + redsm[3][tid] +
                        redsm[4][tid] + redsm[5][tid] + redsm[6][tid] + redsm[7][tid]);
  __syncthreads();

  // ---- PV: wave w owns output dims [16w, 16w+16)
  short8 pf[4];
#pragma unroll
  for (int kc = 0; kc < 4; kc++)
    pf[kc] = *(const short8*)(&P[m16][kc * 32 + q4 * 8]);
  f32x4 o1;
#pragma unroll
  for (int r = 0; r < 4; r++) o1[r] = 0.f;
  {
    int dhl = w * 16 + m16;
#pragma unroll
    for (int kc = 0; kc < 4; kc++) {
      short8 vf = *(const short8*)(Vtile + (size_t)dhl * 128 + kc * 32 + q4 * 8);
      o1 = __builtin_amdgcn_mfma_f32_16x16x32_bf16(pf[kc], vf, o1, 0, 0, 0);
    }
  }
#pragma unroll
  for (int r = 0; r < 4; r++) {
    int row = q4 * 4 + r;
    float val = o1[r] * invd[row];
    Ob[(size_t)(b * 16 + row) * D + h * 128 + w * 16 + m16] = f2bf(val);
  }
}

// ============ kernel 4: O @ Wo split-K=8 + fused per-tile reduction ============
// Each (m,n,z) block stores its fp32 partial, then bumps an arrival counter for
// tile (m,n). The 8th arrival (no spinning — one atomic per block) reads the 8
// L2-hot partials + residual and writes out. Deletes the reduce_wo launch.
__global__ __launch_bounds__(256, 3) void gemm_wo(const u16* __restrict__ Ob,
                                                  const u16* __restrict__ WoT,
                                                  float* __restrict__ Wpart,
                                                  float* __restrict__ out,
                                                  unsigned* __restrict__ cnt) {
  __shared__ u16 smem[2 * 128 * 64];   // 32 KB
  u16* As = smem;
  u16* Bs = smem + 8192;
  int m0 = blockIdx.x * 128, n0 = blockIdx.y * 128;
  int z = blockIdx.z;
  int k0 = z * 256;
  f32x4 acc[4][4];
#pragma unroll
  for (int i = 0; i < 4; i++)
#pragma unroll
    for (int j = 0; j < 4; j++)
#pragma unroll
      for (int r = 0; r < 4; r++) acc[i][j][r] = 0.f;
  gemm_tile(Ob, WoT, false, m0, n0, k0, k0 + 256, As, Bs, acc);
  float* C = Wpart + (size_t)z * 256 * D;
  int tid = threadIdx.x, wid = tid >> 6, lane = tid & 63;
  int q4 = lane >> 4, m16 = lane & 15;
  int wm = wid >> 1, wn = wid & 1;
#pragma unroll
  for (int i = 0; i < 4; i++)
#pragma unroll
    for (int j = 0; j < 4; j++)
#pragma unroll
      for (int r = 0; r < 4; r++) {
        int row = m0 + wm * 64 + i * 16 + q4 * 4 + r;
        int col = n0 + wn * 64 + j * 16 + m16;
        C[(size_t)row * D + col] = acc[i][j][r];
      }

  // ---- split-K finish: last-arriving block reduces this 128x128 tile
  __threadfence();                     // release partial stores (agent scope)
  __syncthreads();
  __shared__ unsigned old_s;
  int tile = blockIdx.x * 16 + blockIdx.y;
  if (tid == 0)
    old_s = __hip_atomic_fetch_add(&cnt[tile], 1u, __ATOMIC_ACQ_REL,
                                   __HIP_MEMORY_SCOPE_AGENT);
  __syncthreads();
  if (old_s == 7u) {
    __threadfence();                   // acquire: see all 8 partials across XCDs
#pragma unroll
    for (int e = 0; e < 16; e++) {
      int idx = e * 256 + tid;         // 4096 float4s in the tile
      int rr = idx >> 5;               // 128 rows x 32 float4/row
      int cc = (idx & 31) * 4;
      size_t off = (size_t)(m0 + rr) * D + n0 + cc;
      float4 s = *(const float4*)(out + off);   // residual base (out = x)
#pragma unroll
      for (int zz = 0; zz < 8; zz++) {
        float4 p = *(const float4*)(Wpart + (size_t)zz * 256 * D + off);
        s.x += p.x; s.y += p.y; s.z += p.z; s.w += p.w;
      }
      *(float4*)(out + off) = s;
    }
  }
}

extern "C" void kernel_launch(void* const* d_in, const int* in_sizes, int n_in,
                              void* d_out, int out_size, void* d_ws, size_t ws_size,
                              hipStream_t stream) {
  const float* x  = (const float*)d_in[0];
  const float* Wq = (const float*)d_in[1];
  const float* Wk = (const float*)d_in[2];
  const float* Wv = (const float*)d_in[3];
  const float* Wo = (const float*)d_in[4];
  float* out = (float*)d_out;
  char* w = (char*)d_ws;
  const size_t MB = 1u << 20;
  u16*   xn    = (u16*)(w);              // 0-8
  u16*   WqT   = (u16*)(w + 8 * MB);     // 8-16
  u16*   WkT   = (u16*)(w + 16 * MB);    // 16-24
  u16*   WvT   = (u16*)(w + 24 * MB);    // 24-32
  u16*   WoT   = (u16*)(w + 32 * MB);    // 32-40
  u16*   K3    = (u16*)(w + 40 * MB);    // 40-48
  u16*   V3    = (u16*)(w + 48 * MB);    // 48-56
  u16*   Obf   = (u16*)(w + 56 * MB);    // 56-57
  unsigned* cnt = (unsigned*)(w + 57 * MB);  // 57: 32 split-K arrival counters
  float* Qp    = (float*)(w + 58 * MB);  // 58-74: Q split-K fp32 partials (8 x 2MB)
  float* Wpart = (float*)(w + 58 * MB);  // aliases Qp: Qp dead before gemm_wo writes

  prep<<<dim3(6144), dim3(256), 0, stream>>>(x, Wq, Wk, Wv, Wo, xn, out, WqT, WkT, WvT, WoT, cnt);
  gemm_mega<<<dim3(768), dim3(256), 0, stream>>>(xn, WkT, WvT, WqT, K3, V3, Qp);
  attn<<<dim3(256), dim3(512), 0, stream>>>(Qp, K3, V3, Obf);
  gemm_wo<<<dim3(2, 16, 8), dim3(256), 0, stream>>>(Obf, WoT, Wpart, out, cnt);
}

// Round 7
// 186.105 us; speedup vs baseline: 1.2604x; 1.2604x over previous
//
#include <hip/hip_runtime.h>

typedef unsigned short u16;
typedef __attribute__((ext_vector_type(8))) short short8;   // 8 bf16 = 4 VGPRs
typedef __attribute__((ext_vector_type(4))) float f32x4;

#define D 2048
#define EPS 1e-5f

__device__ __forceinline__ u16 f2bf(float f) {
  unsigned u = __float_as_uint(f);
  u += 0x7fffu + ((u >> 16) & 1u);   // round-to-nearest-even
  return (u16)(u >> 16);
}

__device__ __forceinline__ void async16(const void* g, void* l) {
  __builtin_amdgcn_global_load_lds(
      (const __attribute__((address_space(1))) void*)g,
      (__attribute__((address_space(3))) void*)l, 16, 0, 0);
}

// ============ kernel 1: fused row-LN (out=x prefill) + weight transpose/cvt ============
__global__ __launch_bounds__(256) void prep(const float* __restrict__ x,
                                            const float* __restrict__ Wq,
                                            const float* __restrict__ Wk,
                                            const float* __restrict__ Wv,
                                            const float* __restrict__ Wo,
                                            u16* __restrict__ xn,
                                            float* __restrict__ out,
                                            u16* __restrict__ WqT, u16* __restrict__ WkT,
                                            u16* __restrict__ WvT, u16* __restrict__ WoT) {
  int bid = blockIdx.x;
  int t = threadIdx.x;
  if (bid < 2048) {
    const float* xr = x + (size_t)bid * D;
    float4 v[2];
    float s = 0.f, sq = 0.f;
#pragma unroll
    for (int i = 0; i < 2; i++) {
      v[i] = *(const float4*)(xr + i * 1024 + t * 4);
      s += v[i].x + v[i].y + v[i].z + v[i].w;
      sq += v[i].x * v[i].x + v[i].y * v[i].y + v[i].z * v[i].z + v[i].w * v[i].w;
    }
#pragma unroll
    for (int m = 32; m >= 1; m >>= 1) { s += __shfl_xor(s, m); sq += __shfl_xor(sq, m); }
    __shared__ float ps[4], pq[4];
    int w = t >> 6, lane = t & 63;
    if (lane == 0) { ps[w] = s; pq[w] = sq; }
    __syncthreads();
    s = ps[0] + ps[1] + ps[2] + ps[3];
    sq = pq[0] + pq[1] + pq[2] + pq[3];
    float mean = s * (1.f / D);
    float var = sq * (1.f / D) - mean * mean;
    float rs = rsqrtf(var + EPS);
    float* outr = out + (size_t)bid * D;
    u16* xnr = xn + (size_t)bid * D;
#pragma unroll
    for (int i = 0; i < 2; i++) {
      *(float4*)(outr + i * 1024 + t * 4) = v[i];      // residual base
      ushort4 o;
      o.x = f2bf((v[i].x - mean) * rs);
      o.y = f2bf((v[i].y - mean) * rs);
      o.z = f2bf((v[i].z - mean) * rs);
      o.w = f2bf((v[i].w - mean) * rs);
      *(ushort4*)(xnr + i * 1024 + t * 4) = o;
    }
  } else {
    int tb = bid - 2048;
    int wsel = tb >> 10;
    int tt = tb & 1023;
    const float* src; u16* dst;
    switch (wsel) {
      case 0: src = Wq; dst = WqT; break;
      case 1: src = Wk; dst = WkT; break;
      case 2: src = Wv; dst = WvT; break;
      default: src = Wo; dst = WoT; break;
    }
    int i0 = (tt >> 5) * 64, j0 = (tt & 31) * 64;
    __shared__ u16 tile[64 * 66];
#pragma unroll
    for (int r = 0; r < 4; r++) {
      int idx = r * 256 + t;
      int row = idx >> 4, c4 = idx & 15;
      float4 v = *(const float4*)(src + (size_t)(i0 + row) * D + j0 + c4 * 4);
      tile[row * 66 + c4 * 4 + 0] = f2bf(v.x);
      tile[row * 66 + c4 * 4 + 1] = f2bf(v.y);
      tile[row * 66 + c4 * 4 + 2] = f2bf(v.z);
      tile[row * 66 + c4 * 4 + 3] = f2bf(v.w);
    }
    __syncthreads();
#pragma unroll
    for (int r = 0; r < 4; r++) {
      int idx = r * 256 + t;
      int row = idx >> 4, c4 = idx & 15;
      ushort4 o;
      o.x = tile[(c4 * 4 + 0) * 66 + row];
      o.y = tile[(c4 * 4 + 1) * 66 + row];
      o.z = tile[(c4 * 4 + 2) * 66 + row];
      o.w = tile[(c4 * 4 + 3) * 66 + row];
      *(ushort4*)(dst + (size_t)(j0 + row) * D + i0 + c4 * 4) = o;   // dst[n][k]=src[k][n]
    }
  }
}

// ============ single-buffered 128x128-tile bf16 MFMA GEMM body (m97 structure) ============
__device__ __forceinline__ void gemm_tile(const u16* __restrict__ A,
                                          const u16* __restrict__ Bt,
                                          bool permB, int m0, int n0,
                                          int kbeg, int kend,
                                          u16* As, u16* Bs, f32x4 acc[4][4]) {
  int tid = threadIdx.x, wid = tid >> 6, lane = tid & 63;
  int q4 = lane >> 4, m16 = lane & 15;
  int wm = wid >> 1, wn = wid & 1;
  for (int kb = kbeg; kb < kend; kb += 64) {
#pragma unroll
    for (int p = 0; p < 4; p++) {
      int idx = p * 256 + tid;         // chunk id 0..1023
      int r = idx >> 3, sl = idx & 7;
      int gc = sl ^ (r & 7);           // XOR-swizzled column chunk
      async16(A + (size_t)(m0 + r) * D + kb + gc * 8, As + (size_t)(p * 256 + wid * 64) * 8);
      int rb = n0 + r;
      int gr = permB ? ((rb & 127) * 16 + (rb >> 7)) : rb;  // token perm for V
      async16(Bt + (size_t)gr * D + kb + gc * 8, Bs + (size_t)(p * 256 + wid * 64) * 8);
    }
    __syncthreads();
#pragma unroll
    for (int ks = 0; ks < 2; ks++) {
      short8 af[4], bf[4];
      int c = ks * 4 + q4;
#pragma unroll
      for (int i = 0; i < 4; i++) {
        int ra = wm * 64 + i * 16 + m16;
        af[i] = *(const short8*)(As + ra * 64 + (c ^ (ra & 7)) * 8);
        int rb = wn * 64 + i * 16 + m16;
        bf[i] = *(const short8*)(Bs + rb * 64 + (c ^ (rb & 7)) * 8);
      }
#pragma unroll
      for (int i = 0; i < 4; i++)
#pragma unroll
        for (int j = 0; j < 4; j++)
          acc[i][j] = __builtin_amdgcn_mfma_f32_16x16x32_bf16(af[i], bf[j], acc[i][j], 0, 0, 0);
    }
    __syncthreads();
  }
}

// ============ kernel 2: K/V/Q mega-GEMM, 768 blocks = exactly 3/CU, balanced ============
// bid [0,512):   K/V full tiles (XCD-chunked swizzle), 32 K-steps each
// bid [512,768): Q split-K tiles: 2 m-tiles x 16 n-tiles x splitK=8, 4 K-steps each,
//                fp32 partials into Qp. Per-CU load: 2 fulls + 1 Q = 2.125 units.
__global__ __launch_bounds__(256, 3) void gemm_mega(const u16* __restrict__ xn,
                                                    const u16* __restrict__ WkT,
                                                    const u16* __restrict__ WvT,
                                                    const u16* __restrict__ WqT,
                                                    u16* __restrict__ K3,
                                                    u16* __restrict__ V3,
                                                    float* __restrict__ Qp) {
  __shared__ u16 smem[2 * 128 * 64];   // 32 KB
  u16* As = smem;
  u16* Bs = smem + 8192;
  int bid0 = blockIdx.x;
  int tid = threadIdx.x, wid = tid >> 6, lane = tid & 63;
  int q4 = lane >> 4, m16 = lane & 15;
  int wm = wid >> 1, wn = wid & 1;

  if (bid0 >= 512) {
    // ---- Q split-K blocks (1/8 weight) ----
    int qb = bid0 - 512;
    int ks = qb & 7, t = qb >> 3;            // ks: K-slice; t in [0,32)
    int m0 = (t >> 4) * 128, n0 = (t & 15) * 128;
    f32x4 acc[4][4];
#pragma unroll
    for (int i = 0; i < 4; i++)
#pragma unroll
      for (int j = 0; j < 4; j++)
#pragma unroll
        for (int r = 0; r < 4; r++) acc[i][j][r] = 0.f;
    gemm_tile(xn, WqT, false, m0, n0, ks * 256, ks * 256 + 256, As, Bs, acc);
    float* C = Qp + (size_t)ks * 256 * D;
#pragma unroll
    for (int i = 0; i < 4; i++)
#pragma unroll
      for (int j = 0; j < 4; j++)
#pragma unroll
        for (int r = 0; r < 4; r++) {
          int row = m0 + wm * 64 + i * 16 + q4 * 4 + r;
          int col = n0 + wn * 64 + j * 16 + m16;
          C[(size_t)row * D + col] = acc[i][j][r];
        }
    return;
  }

  int bid = (bid0 & 7) * 64 + (bid0 >> 3);   // bijective XCD chunking: 512 % 8 == 0
  int sel = bid >> 8;                  // 0: K-GEMM, 1: V-GEMM
  int z = bid & 255;
  int m0 = (z >> 4) * 128, n0 = (z & 15) * 128;
  const u16* A = sel ? WvT : xn;
  const u16* Bt = sel ? xn : WkT;
  f32x4 acc[4][4];
#pragma unroll
  for (int i = 0; i < 4; i++)
#pragma unroll
    for (int j = 0; j < 4; j++)
#pragma unroll
      for (int r = 0; r < 4; r++) acc[i][j][r] = 0.f;
  gemm_tile(A, Bt, sel == 1, m0, n0, 0, D, As, Bs, acc);

  if (sel == 1) {
    int h = m0 >> 7, b = n0 >> 7;
#pragma unroll
    for (int i = 0; i < 4; i++)
#pragma unroll
      for (int j = 0; j < 4; j++)
#pragma unroll
        for (int r = 0; r < 4; r++) {
          int dhl = wm * 64 + i * 16 + q4 * 4 + r;     // C/D: row=(lane>>4)*4+reg
          int key = wn * 64 + j * 16 + m16;            //      col=lane&15
          V3[((size_t)(h * 16 + b) * 128 + dhl) * 128 + key] = f2bf(acc[i][j][r]);
        }
  } else {
    // fused head-LN: rows = tokens, 128 cols = this head's dims (tile-aligned)
    float* redS = (float*)smem;        // [128][2]
    float* redQ = redS + 256;          // [128][2]
    __syncthreads();                   // smem free for reduction scratch
#pragma unroll
    for (int i = 0; i < 4; i++) {      // i-by-i to limit register liveness
      float ps[4], pq[4];
#pragma unroll
      for (int r = 0; r < 4; r++) {
        float s = 0.f, q = 0.f;
#pragma unroll
        for (int j = 0; j < 4; j++) { float a = acc[i][j][r]; s += a; q += a * a; }
#pragma unroll
        for (int msk = 1; msk < 16; msk <<= 1) {
          s += __shfl_xor(s, msk);
          q += __shfl_xor(q, msk);
        }
        ps[r] = s; pq[r] = q;
      }
      if (m16 == 0) {
#pragma unroll
        for (int r = 0; r < 4; r++) {
          int row = wm * 64 + i * 16 + q4 * 4 + r;
          redS[row * 2 + wn] = ps[r];
          redQ[row * 2 + wn] = pq[r];
        }
      }
    }
    __syncthreads();
    int h = n0 >> 7;
#pragma unroll
    for (int i = 0; i < 4; i++)
#pragma unroll
      for (int r = 0; r < 4; r++) {
        int row = wm * 64 + i * 16 + q4 * 4 + r;
        float S = redS[row * 2] + redS[row * 2 + 1];
        float Qs = redQ[row * 2] + redQ[row * 2 + 1];
        float mean = S * (1.f / 128.f);
        float var = Qs * (1.f / 128.f) - mean * mean;
        float rstd = rsqrtf(var + EPS);
        int tok = m0 + row;
#pragma unroll
        for (int j = 0; j < 4; j++) {
          int dhl = wn * 64 + j * 16 + m16;
          u16 val = f2bf((acc[i][j][r] - mean) * rstd);
          K3[(((size_t)(h * 16 + (tok & 15))) * 128 + (tok >> 4)) * 128 + dhl] = val;
        }
      }
  }
}

// ============ kernel 3: attention, 256 blocks=(b,h), 512 threads (8 waves) ============
// T14 async-split: K/V fragment addresses depend on nothing -> issue all 8 global
// loads at kernel entry; their latency hides under the Qp reduce + head-LN + barrier.
// QK^T and PV then consume registers directly.
__global__ __launch_bounds__(512) void attn(const float* __restrict__ Qp,
                                            const u16* __restrict__ K3,
                                            const u16* __restrict__ V3,
                                            u16* __restrict__ Ob) {
  int bh = blockIdx.x;
  int h = bh & 15, b = bh >> 4;
  int tid = threadIdx.x, w = tid >> 6, lane = tid & 63;
  int q4 = lane >> 4, m16 = lane & 15;
  __shared__ u16 Qs[16][136];
  __shared__ u16 P[16][136];
  __shared__ float redmx[8][16];
  __shared__ float redsm[8][16];
  __shared__ float invd[16];
  const float scale = 0.08838834764831845f;   // 1/sqrt(128)
  const u16* Ktile = K3 + (size_t)(h * 16 + b) * 128 * 128;
  const u16* Vtile = V3 + (size_t)(h * 16 + b) * 128 * 128;

  // ---- prefetch K & V fragments into registers (issue-early, consume-late)
  short8 bf[4], vf[4];
  {
    int kv = w * 16 + m16;             // key for QK^T == dhl for PV (same formula)
#pragma unroll
    for (int dc = 0; dc < 4; dc++)
      bf[dc] = *(const short8*)(Ktile + (size_t)kv * 128 + dc * 32 + q4 * 8);
#pragma unroll
    for (int kc = 0; kc < 4; kc++)
      vf[kc] = *(const short8*)(Vtile + (size_t)kv * 128 + kc * 32 + q4 * 8);
  }

  // ---- Qp reduce + head-LN: thread (row=tid>>5, 4 cols at (tid&31)*4)
  {
    int row = tid >> 5;
    int c4 = (tid & 31) * 4;
    const float* qpb = Qp + (size_t)(b * 16 + row) * D + h * 128 + c4;
    float q4v[4] = {0.f, 0.f, 0.f, 0.f};
#pragma unroll
    for (int ks = 0; ks < 8; ks++) {
      float4 a = *(const float4*)(qpb + (size_t)ks * 256 * D);
      q4v[0] += a.x; q4v[1] += a.y; q4v[2] += a.z; q4v[3] += a.w;
    }
    float s = 0.f, sq = 0.f;
#pragma unroll
    for (int ii = 0; ii < 4; ii++) { s += q4v[ii]; sq += q4v[ii] * q4v[ii]; }
#pragma unroll
    for (int msk = 1; msk < 32; msk <<= 1) { s += __shfl_xor(s, msk); sq += __shfl_xor(sq, msk); }
    float mean = s * (1.f / 128.f);
    float var = sq * (1.f / 128.f) - mean * mean;
    float rstd = rsqrtf(var + EPS);
    ushort4 o4;
    o4.x = f2bf((q4v[0] - mean) * rstd);
    o4.y = f2bf((q4v[1] - mean) * rstd);
    o4.z = f2bf((q4v[2] - mean) * rstd);
    o4.w = f2bf((q4v[3] - mean) * rstd);
    *(ushort4*)(&Qs[row][c4]) = o4;
  }
  __syncthreads();

  // ---- QK^T: wave w handles keys [16w, 16w+16), K fragments already in regs
  short8 af[4];
#pragma unroll
  for (int dc = 0; dc < 4; dc++)
    af[dc] = *(const short8*)(&Qs[m16][dc * 32 + q4 * 8]);
  f32x4 s1;
#pragma unroll
  for (int r = 0; r < 4; r++) s1[r] = 0.f;
#pragma unroll
  for (int dc = 0; dc < 4; dc++)
    s1 = __builtin_amdgcn_mfma_f32_16x16x32_bf16(af[dc], bf[dc], s1, 0, 0, 0);
  float mx[4];
#pragma unroll
  for (int r = 0; r < 4; r++) {
    mx[r] = s1[r];
#pragma unroll
    for (int msk = 1; msk < 16; msk <<= 1) mx[r] = fmaxf(mx[r], __shfl_xor(mx[r], msk));
    if (m16 == 0) redmx[w][q4 * 4 + r] = mx[r];
  }
  __syncthreads();
#pragma unroll
  for (int r = 0; r < 4; r++) {
    int row = q4 * 4 + r;
    float M = fmaxf(fmaxf(fmaxf(redmx[0][row], redmx[1][row]), fmaxf(redmx[2][row], redmx[3][row])),
                    fmaxf(fmaxf(redmx[4][row], redmx[5][row]), fmaxf(redmx[6][row], redmx[7][row])));
    float e = __expf((s1[r] - M) * scale);
    s1[r] = e;
    float acc = e;
#pragma unroll
    for (int msk = 1; msk < 16; msk <<= 1) acc += __shfl_xor(acc, msk);
    if (m16 == 0) redsm[w][row] = acc;
  }
#pragma unroll
  for (int r = 0; r < 4; r++)
    P[q4 * 4 + r][w * 16 + m16] = f2bf(s1[r]);
  __syncthreads();
  if (tid < 16)
    invd[tid] = 1.0f / (redsm[0][tid] + redsm[1][tid] + redsm[2][tid] + redsm[3][tid] +
                        redsm[4][tid] + redsm[5][tid] + redsm[6][tid] + redsm[7][tid]);
  __syncthreads();

  // ---- PV: wave w owns output dims [16w, 16w+16), V fragments already in regs
  short8 pf[4];
#pragma unroll
  for (int kc = 0; kc < 4; kc++)
    pf[kc] = *(const short8*)(&P[m16][kc * 32 + q4 * 8]);
  f32x4 o1;
#pragma unroll
  for (int r = 0; r < 4; r++) o1[r] = 0.f;
#pragma unroll
  for (int kc = 0; kc < 4; kc++)
    o1 = __builtin_amdgcn_mfma_f32_16x16x32_bf16(pf[kc], vf[kc], o1, 0, 0, 0);
#pragma unroll
  for (int r = 0; r < 4; r++) {
    int row = q4 * 4 + r;
    float val = o1[r] * invd[row];
    Ob[(size_t)(b * 16 + row) * D + h * 128 + w * 16 + m16] = f2bf(val);
  }
}

// ============ kernel 4: Wpart[z] = O @ Wo[z-slice]  (split-K=8, plain stores) ============
__global__ __launch_bounds__(256, 3) void gemm_wo(const u16* __restrict__ Ob,
                                                  const u16* __restrict__ WoT,
                                                  float* __restrict__ Wpart) {
  __shared__ u16 smem[2 * 128 * 64];   // 32 KB
  u16* As = smem;
  u16* Bs = smem + 8192;
  int m0 = blockIdx.x * 128, n0 = blockIdx.y * 128;
  int z = blockIdx.z;
  int k0 = z * 256;
  f32x4 acc[4][4];
#pragma unroll
  for (int i = 0; i < 4; i++)
#pragma unroll
    for (int j = 0; j < 4; j++)
#pragma unroll
      for (int r = 0; r < 4; r++) acc[i][j][r] = 0.f;
  gemm_tile(Ob, WoT, false, m0, n0, k0, k0 + 256, As, Bs, acc);
  float* C = Wpart + (size_t)z * 256 * D;
  int tid = threadIdx.x, wid = tid >> 6, lane = tid & 63;
  int q4 = lane >> 4, m16 = lane & 15;
  int wm = wid >> 1, wn = wid & 1;
#pragma unroll
  for (int i = 0; i < 4; i++)
#pragma unroll
    for (int j = 0; j < 4; j++)
#pragma unroll
      for (int r = 0; r < 4; r++) {
        int row = m0 + wm * 64 + i * 16 + q4 * 4 + r;
        int col = n0 + wn * 64 + j * 16 + m16;
        C[(size_t)row * D + col] = acc[i][j][r];
      }
}

// ============ kernel 5: out[0:256] += sum_z Wpart[z]  (vectorized, no atomics) ============
__global__ __launch_bounds__(256) void reduce_wo(const float* __restrict__ Wpart,
                                                 float* __restrict__ out) {
  int i = (blockIdx.x * 256 + threadIdx.x) * 4;   // 512 blocks cover 256*2048 elems
  float4 s = *(const float4*)(out + i);           // residual base (out = x)
#pragma unroll
  for (int z = 0; z < 8; z++) {
    float4 p = *(const float4*)(Wpart + (size_t)z * 256 * D + i);
    s.x += p.x; s.y += p.y; s.z += p.z; s.w += p.w;
  }
  *(float4*)(out + i) = s;
}

extern "C" void kernel_launch(void* const* d_in, const int* in_sizes, int n_in,
                              void* d_out, int out_size, void* d_ws, size_t ws_size,
                              hipStream_t stream) {
  const float* x  = (const float*)d_in[0];
  const float* Wq = (const float*)d_in[1];
  const float* Wk = (const float*)d_in[2];
  const float* Wv = (const float*)d_in[3];
  const float* Wo = (const float*)d_in[4];
  float* out = (float*)d_out;
  char* w = (char*)d_ws;
  const size_t MB = 1u << 20;
  u16*   xn    = (u16*)(w);              // 0-8
  u16*   WqT   = (u16*)(w + 8 * MB);     // 8-16
  u16*   WkT   = (u16*)(w + 16 * MB);    // 16-24
  u16*   WvT   = (u16*)(w + 24 * MB);    // 24-32
  u16*   WoT   = (u16*)(w + 32 * MB);    // 32-40
  u16*   K3    = (u16*)(w + 40 * MB);    // 40-48
  u16*   V3    = (u16*)(w + 48 * MB);    // 48-56
  u16*   Obf   = (u16*)(w + 56 * MB);    // 56-57
  float* Qp    = (float*)(w + 58 * MB);  // 58-74: Q split-K fp32 partials (8 x 2MB)
  float* Wpart = (float*)(w + 58 * MB);  // aliases Qp: Qp dead before gemm_wo writes

  prep<<<dim3(6144), dim3(256), 0, stream>>>(x, Wq, Wk, Wv, Wo, xn, out, WqT, WkT, WvT, WoT);
  gemm_mega<<<dim3(768), dim3(256), 0, stream>>>(xn, WkT, WvT, WqT, K3, V3, Qp);
  attn<<<dim3(256), dim3(512), 0, stream>>>(Qp, K3, V3, Obf);
  gemm_wo<<<dim3(2, 16, 8), dim3(256), 0, stream>>>(Obf, WoT, Wpart);
  reduce_wo<<<dim3(512), dim3(256), 0, stream>>>(Wpart, out);
}